// Round 7
// baseline (1585.630 us; speedup 1.0000x reference)
//
#include <hip/hip_runtime.h>
#include <hip/hip_bf16.h>
#include <math.h>

// TitanLongTermMemory — round 7.
// r6: attn 117us x4 (MfmaUtil 3.3%, latency-bound: 320 scalar ds_read/lane in
// PV, 2B scattered stores, 4 waves/CU), GEMMs ~750us at 1 block/CU.
// This round: (1) attn computes O^T = V^T P^T so PV A-frags (transposed-V) and
// B-frags (row-major P) are both ds_read_b128; 8 waves with QK || V-transpose
// overlap; 8B packed out stores. (2) KV projections merged to N=2048 GEMMs.
// (3) exact (non-pow2) ws chunking keeps GEMM grids large.

using bf16 = __hip_bfloat16;

typedef __attribute__((ext_vector_type(8))) short bf16x8;
typedef __attribute__((ext_vector_type(4))) float f32x4;

__device__ __forceinline__ float ldf(const bf16* p) { return __bfloat162float(*p); }
__device__ __forceinline__ float ldf(const float* p) { return *p; }
__device__ __forceinline__ void stf(bf16* p, float v) { *p = __float2bfloat16(v); }
__device__ __forceinline__ void stf(float* p, float v) { *p = v; }
__device__ __forceinline__ float b2f(const bf16& b) { return __bfloat162float(b); }

enum { ACT_NONE = 0, ACT_SILU = 1, ACT_SIGMOID = 2 };

__global__ void detect_kernel(const unsigned short* g, int* flag) {
  if (threadIdx.x == 0) *flag = (g[0] != 0) ? 1 : 0;
}

__global__ __launch_bounds__(256) void conv_kernel(
    const void* __restrict__ src, bf16* __restrict__ dst, int n, size_t src_off,
    const int* __restrict__ flag) {
  int i = blockIdx.x * 256 + threadIdx.x;
  if (i >= n) return;
  if (*flag) dst[i] = ((const bf16*)src)[src_off + i];
  else dst[i] = __float2bfloat16(((const float*)src)[src_off + i]);
}

__global__ __launch_bounds__(256) void pack_bias2(
    const bf16* __restrict__ bk, const bf16* __restrict__ bv, bf16* __restrict__ o) {
  int j = blockIdx.x * 256 + threadIdx.x;
  if (j >= 2048) return;
  o[j] = (j < 1024) ? bk[j] : bv[j - 1024];
}

// ---------------- MFMA GEMM: C[M,N] = act(A[M,K] @ B[N,K]^T + bias) ----------
__device__ __forceinline__ void gl_lds16(const short* g, short* l) {
  __builtin_amdgcn_global_load_lds(
      (const __attribute__((address_space(1))) void*)g,
      (__attribute__((address_space(3))) void*)l, 16, 0, 0);
}

template <typename TC, int ACT, bool HAS_BIAS>
__global__ __launch_bounds__(256) void mgemm(
    const bf16* __restrict__ Ab, const bf16* __restrict__ Bw,
    const bf16* __restrict__ bias, TC* __restrict__ C,
    int M, int N, int K, int lda, int ldc)
{
  __shared__ short As[128 * 32];
  __shared__ short Bs[128 * 32];
  const short* A = (const short*)Ab;
  const short* B = (const short*)Bw;
  const int tid = threadIdx.x;
  const int m0 = blockIdx.y * 128, n0 = blockIdx.x * 128;
  const int wave = tid >> 6, lane = tid & 63;
  const int wm = (wave & 1) * 64, wn = (wave >> 1) * 64;
  const int fm = lane & 15;
  const int fk = (lane >> 4) * 8;

  const int srow = tid >> 2, scol = (tid & 3) * 8;
  const short* gA0 = A + (size_t)(m0 + srow) * lda + scol;
  const short* gA1 = A + (size_t)(m0 + 64 + srow) * lda + scol;
  const short* gB0 = B + (size_t)(n0 + srow) * K + scol;
  const short* gB1 = B + (size_t)(n0 + 64 + srow) * K + scol;
  short* lA0 = As + tid * 8;
  short* lA1 = As + (256 + tid) * 8;
  short* lB0 = Bs + tid * 8;
  short* lB1 = Bs + (256 + tid) * 8;

  f32x4 acc[4][4] = {};

  for (int k0 = 0; k0 < K; k0 += 32) {
    gl_lds16(gA0 + k0, lA0);
    gl_lds16(gA1 + k0, lA1);
    gl_lds16(gB0 + k0, lB0);
    gl_lds16(gB1 + k0, lB1);
    __syncthreads();
    bf16x8 af[4], bfr[4];
#pragma unroll
    for (int i = 0; i < 4; ++i)
      af[i] = *(const bf16x8*)&As[(wm + i * 16 + fm) * 32 + fk];
#pragma unroll
    for (int j = 0; j < 4; ++j)
      bfr[j] = *(const bf16x8*)&Bs[(wn + j * 16 + fm) * 32 + fk];
#pragma unroll
    for (int i = 0; i < 4; ++i)
#pragma unroll
      for (int j = 0; j < 4; ++j)
        acc[i][j] = __builtin_amdgcn_mfma_f32_16x16x32_bf16(af[i], bfr[j], acc[i][j], 0, 0, 0);
    __syncthreads();
  }

  const int rg = (lane >> 4) * 4;
#pragma unroll
  for (int i = 0; i < 4; ++i) {
#pragma unroll
    for (int j = 0; j < 4; ++j) {
      const int n = n0 + wn + j * 16 + fm;
      float bv = 0.f;
      if (HAS_BIAS) bv = b2f(bias[n]);
#pragma unroll
      for (int r = 0; r < 4; ++r) {
        const int m = m0 + wm + i * 16 + rg + r;
        float v = acc[i][j][r] + bv;
        if (ACT == ACT_SILU) v = v / (1.f + __expf(-v));
        if (ACT == ACT_SIGMOID) v = 1.f / (1.f + __expf(-v));
        stf(&C[(size_t)m * ldc + n], v);
      }
    }
  }
}

// ---------------- VALU GEMM (preamble weight combines, M=4 rows) -------------
template <typename TA, typename TC, int ACT, bool TRANS_B>
__global__ __launch_bounds__(256) void gemm_kernel(
    const TA* __restrict__ A, const bf16* __restrict__ B,
    const bf16* __restrict__ bias, TC* __restrict__ C,
    int M, int N, int K)
{
  __shared__ float As[16][68];
  __shared__ float Bs[16][68];
  const int tid = threadIdx.x;
  const int tx = tid & 15;
  const int ty = tid >> 4;
  const int m0 = blockIdx.y * 64;
  const int n0 = blockIdx.x * 64;

  float acc[4][4] = {};

  for (int k0 = 0; k0 < K; k0 += 16) {
#pragma unroll
    for (int i = 0; i < 4; ++i) {
      int e = tid + 256 * i;
      int m = e >> 4, kk = e & 15;
      float v = 0.f;
      if (m0 + m < M) v = ldf(&A[(size_t)(m0 + m) * K + k0 + kk]);
      As[kk][m] = v;
    }
#pragma unroll
    for (int i = 0; i < 4; ++i) {
      int e = tid + 256 * i;
      if (TRANS_B) {
        int n = e >> 4, kk = e & 15;
        float v = 0.f;
        if (n0 + n < N) v = ldf(&B[(size_t)(n0 + n) * K + k0 + kk]);
        Bs[kk][n] = v;
      } else {
        int kk = e >> 6, n = e & 63;
        float v = 0.f;
        if (n0 + n < N) v = ldf(&B[(size_t)(k0 + kk) * N + n0 + n]);
        Bs[kk][n] = v;
      }
    }
    __syncthreads();
#pragma unroll
    for (int kk = 0; kk < 16; ++kk) {
      const float4 av = *reinterpret_cast<const float4*>(&As[kk][ty * 4]);
      const float4 bv = *reinterpret_cast<const float4*>(&Bs[kk][tx * 4]);
      const float a[4] = {av.x, av.y, av.z, av.w};
      const float b[4] = {bv.x, bv.y, bv.z, bv.w};
#pragma unroll
      for (int i = 0; i < 4; ++i)
#pragma unroll
        for (int j = 0; j < 4; ++j) acc[i][j] += a[i] * b[j];
    }
    __syncthreads();
  }

#pragma unroll
  for (int i = 0; i < 4; ++i) {
    int m = m0 + ty * 4 + i;
    if (m >= M) continue;
#pragma unroll
    for (int j = 0; j < 4; ++j) {
      int n = n0 + tx * 4 + j;
      if (n >= N) continue;
      float v = acc[i][j];
      if (bias) v += b2f(bias[n]);
      if (ACT == ACT_SILU) v = v / (1.f + __expf(-v));
      if (ACT == ACT_SIGMOID) v = 1.f / (1.f + __expf(-v));
      stf(&C[(size_t)m * N + n], v);
    }
  }
}

// Row LayerNorm over width W; optional post-LN add of a bf16 vector.
template <typename TI, typename TO, bool ADD, int W, int BS>
__global__ __launch_bounds__(BS) void ln_kernel(
    const TI* __restrict__ in, const bf16* __restrict__ g, const bf16* __restrict__ b,
    const bf16* __restrict__ addv, TO* __restrict__ out)
{
  __shared__ float red[BS];
  const int row = blockIdx.x;
  const TI* rin = in + (size_t)row * W;
  TO* rout = out + (size_t)row * W;
  const int NP = W / BS;
  float v[NP];
  float s = 0.f;
#pragma unroll
  for (int i = 0; i < NP; ++i) { v[i] = ldf(&rin[threadIdx.x + i * BS]); s += v[i]; }
  red[threadIdx.x] = s; __syncthreads();
  for (int o = BS / 2; o > 0; o >>= 1) {
    if (threadIdx.x < o) red[threadIdx.x] += red[threadIdx.x + o];
    __syncthreads();
  }
  const float mean = red[0] / W;
  __syncthreads();
  float sq = 0.f;
#pragma unroll
  for (int i = 0; i < NP; ++i) { float d = v[i] - mean; sq += d * d; }
  red[threadIdx.x] = sq; __syncthreads();
  for (int o = BS / 2; o > 0; o >>= 1) {
    if (threadIdx.x < o) red[threadIdx.x] += red[threadIdx.x + o];
    __syncthreads();
  }
  const float rstd = rsqrtf(red[0] / W + 1e-5f);
#pragma unroll
  for (int i = 0; i < NP; ++i) {
    int c = threadIdx.x + i * BS;
    float o_ = (v[i] - mean) * rstd * b2f(g[c]) + b2f(b[c]);
    if (ADD) o_ += b2f(addv[c]);
    stf(&rout[c], o_);
  }
}

// ---------------- MFMA attention v3: one block per (segment, head) ----------
// K/V sources are packed [row][k(1024)|v(1024)] stride 2048 (KVr / KVx).
// PV computes O^T = V^T @ P^T: A-frags from transposed V, B-frags from
// row-major P — all ds_read_b128. 8 waves: 0-3 QK+softmax, 4-7 V-transpose.
__global__ __launch_bounds__(512) void attn_kernel(
    const bf16* __restrict__ qg, const bf16* __restrict__ krv,
    const bf16* __restrict__ kxv, const bf16* __restrict__ kpg,
    const bf16* __restrict__ vpg, bf16* __restrict__ outg)
{
  __shared__ short qs[4 * 64 * 32];    // Q tiles [kb][s][32]
  __shared__ short ksl[4 * 144 * 32];  // K tiles [kb][t][32], t>=132 masked
  __shared__ short vt[128 * 168];      // V^T [d][t], t in [132,164) zeroed
  __shared__ short pl[64 * 168];       // P [s][t] row-major, t in [132,160)=0

  const int tid = threadIdx.x;
  const int seg = blockIdx.x >> 3, h = blockIdx.x & 7;
  const unsigned short* q = (const unsigned short*)qg;
  const unsigned short* kv_r = (const unsigned short*)krv;
  const unsigned short* kv_x = (const unsigned short*)kxv;
  const unsigned short* kp = (const unsigned short*)kpg;
  const unsigned short* vp = (const unsigned short*)vpg;
  const size_t qbase = (size_t)seg * 64 * 1024 + h * 128;
  const size_t rbase = (size_t)seg * 64 * 2048 + h * 128;

  for (int ch = tid; ch < 64 * 16; ch += 512) {
    int row = ch >> 4, k8 = ch & 15;
    uint4 v = *(const uint4*)(q + qbase + (size_t)row * 1024 + k8 * 8);
    *(uint4*)&qs[((k8 >> 2) * 64 + row) * 32 + (k8 & 3) * 8] = v;
  }
  for (int ch = tid; ch < 132 * 16; ch += 512) {
    int t = ch >> 4, k8 = ch & 15;
    const unsigned short* src;
    if (t < 64) src = kv_r + rbase + (size_t)t * 2048;
    else if (t < 68) src = kp + (size_t)(t - 64) * 1024 + h * 128;
    else src = kv_x + rbase + (size_t)(t - 68) * 2048;
    uint4 v = *(const uint4*)(src + k8 * 8);
    *(uint4*)&ksl[((k8 >> 2) * 144 + t) * 32 + (k8 & 3) * 8] = v;
  }
  __syncthreads();

  const int wave = tid >> 6, lane = tid & 63;
  const int fm = lane & 15, fq = lane >> 4;

  if (wave < 4) {
    const int s0 = wave * 16;
    f32x4 acc[10];
#pragma unroll
    for (int tt = 0; tt < 10; ++tt) acc[tt] = (f32x4){0.f, 0.f, 0.f, 0.f};
#pragma unroll
    for (int kb = 0; kb < 4; ++kb) {
      const bf16x8 a = *(const bf16x8*)&qs[(kb * 64 + s0 + fm) * 32 + fq * 8];
#pragma unroll
      for (int tt = 0; tt < 9; ++tt) {
        const bf16x8 b = *(const bf16x8*)&ksl[(kb * 144 + tt * 16 + fm) * 32 + fq * 8];
        acc[tt] = __builtin_amdgcn_mfma_f32_16x16x32_bf16(a, b, acc[tt], 0, 0, 0);
      }
    }
    const float scale = 0.08838834764831845f;  // 1/sqrt(128)
#pragma unroll
    for (int r = 0; r < 4; ++r) {
      float m = -3.0e38f;
#pragma unroll
      for (int tt = 0; tt < 9; ++tt) {
        int t = tt * 16 + fm;
        if (t < 132) m = fmaxf(m, acc[tt][r] * scale);
      }
      for (int d = 1; d < 16; d <<= 1) m = fmaxf(m, __shfl_xor(m, d));
      float e[10];
      float sum = 0.f;
#pragma unroll
      for (int tt = 0; tt < 10; ++tt) {
        int t = tt * 16 + fm;
        float ev = 0.f;
        if (t < 132) ev = __expf(acc[tt][r] * scale - m);
        e[tt] = ev; sum += ev;
      }
      for (int d = 1; d < 16; d <<= 1) sum += __shfl_xor(sum, d);
      const float inv = 1.f / sum;
      const int s = s0 + fq * 4 + r;
#pragma unroll
      for (int tt = 0; tt < 10; ++tt) {
        bf16 pv = __float2bfloat16(e[tt] * inv);
        pl[s * 168 + tt * 16 + fm] = *(const short*)&pv;
      }
    }
  } else {
    // transpose-stage V: vt[d][t] = V[t][d]
    for (int ch = tid - 256; ch < 132 * 32; ch += 256) {
      int t = ch >> 5, d4 = (ch & 31) * 4;
      const unsigned short* src;
      if (t < 64) src = kv_r + rbase + 1024 + (size_t)t * 2048;
      else if (t < 68) src = vp + (size_t)(t - 64) * 1024 + h * 128;
      else src = kv_x + rbase + 1024 + (size_t)(t - 68) * 2048;
      uint2 w = *(const uint2*)(src + d4);
      vt[(d4 + 0) * 168 + t] = (short)(w.x & 0xffffu);
      vt[(d4 + 1) * 168 + t] = (short)(w.x >> 16);
      vt[(d4 + 2) * 168 + t] = (short)(w.y & 0xffffu);
      vt[(d4 + 3) * 168 + t] = (short)(w.y >> 16);
    }
    for (int ch = tid - 256; ch < 128 * 32; ch += 256) {
      int d = ch >> 5, tp = 132 + (ch & 31);
      vt[d * 168 + tp] = 0;
    }
  }
  __syncthreads();

  // PV: O^T tiles; wave = d-tile (8), 4 s-tiles each, 5 k-blocks of 32
  const int dt = wave;
  bf16x8 af[5];
#pragma unroll
  for (int kb = 0; kb < 5; ++kb)
    af[kb] = *(const bf16x8*)&vt[(dt * 16 + fm) * 168 + kb * 32 + fq * 8];
#pragma unroll
  for (int st = 0; st < 4; ++st) {
    f32x4 o = (f32x4){0.f, 0.f, 0.f, 0.f};
#pragma unroll
    for (int kb = 0; kb < 5; ++kb) {
      const bf16x8 bp = *(const bf16x8*)&pl[(st * 16 + fm) * 168 + kb * 32 + fq * 8];
      o = __builtin_amdgcn_mfma_f32_16x16x32_bf16(af[kb], bp, o, 0, 0, 0);
    }
    // D[d][s]: col(lane&15)=s, row(quad*4+r)=d -> pack 4 consecutive d, 8B store
    const int s = st * 16 + fm;
    bf16 b0 = __float2bfloat16(o[0]), b1 = __float2bfloat16(o[1]);
    bf16 b2 = __float2bfloat16(o[2]), b3 = __float2bfloat16(o[3]);
    uint2 w;
    w.x = ((unsigned)(*(unsigned short*)&b1) << 16) | (*(unsigned short*)&b0);
    w.y = ((unsigned)(*(unsigned short*)&b3) << 16) | (*(unsigned short*)&b2);
    *(uint2*)((unsigned short*)outg + qbase + (size_t)s * 1024 + dt * 16 + fq * 4) = w;
  }
}

// t = gate * ao + x (x read from raw input with dtype flag)
__global__ __launch_bounds__(256) void combine_kernel(
    const bf16* __restrict__ g, const bf16* __restrict__ a,
    const void* __restrict__ xsrc, size_t xoff, const int* __restrict__ flag,
    bf16* __restrict__ o, int n)
{
  int i = blockIdx.x * 256 + threadIdx.x;
  if (i >= n) return;
  float x = *flag ? b2f(((const bf16*)xsrc)[xoff + i])
                  : ((const float*)xsrc)[xoff + i];
  o[i] = __float2bfloat16(b2f(g[i]) * b2f(a[i]) + x);
}

extern "C" void kernel_launch(void* const* d_in, const int* in_sizes, int n_in,
                              void* d_out, int out_size, void* d_ws, size_t ws_size,
                              hipStream_t stream)
{
  (void)n_in; (void)out_size;
  const int R = 16384, Cd = 1024, Md = 128;

  char* ws = (char*)d_ws;
  size_t off = 0;
  auto alloc = [&](size_t bytes) -> void* {
    void* p = ws + off;
    off += (bytes + 255) & ~(size_t)255;
    return p;
  };

  int* flag = (int*)alloc(256);
  bf16* nb[30];
  nb[0] = nullptr;
  for (int i = 1; i < 30; ++i) nb[i] = (bf16*)alloc((size_t)in_sizes[i] * sizeof(bf16));
  bf16* Wkv   = (bf16*)alloc((size_t)2 * Cd * Cd * sizeof(bf16));  // [Wkk|Wvv] rows
  bf16* bias2 = (bf16*)alloc(2048 * sizeof(bf16));                 // [bk|bv]
  bf16* kp    = (bf16*)alloc((size_t)4 * Cd * sizeof(bf16));
  bf16* vp    = (bf16*)alloc((size_t)4 * Cd * sizeof(bf16));
  const size_t fixed_end = off;

  // exact chunk sizing (multiple of 128 rows); per-row scratch = 16896 B
  size_t avail = (ws_size > fixed_end + (1u << 20)) ? (ws_size - fixed_end - (1u << 20)) : 0;
  long crl = (long)(avail / 16896);
  int CR = (int)(crl - (crl % 128));
  if (CR > R) CR = R;
  if (CR < 128) CR = 128;

  const size_t RB = (size_t)CR * Cd * sizeof(bf16);
  bf16* Xc  = (bf16*)alloc(RB);          // x(bf16) -> q
  bf16* QS  = (bf16*)alloc(RB);          // q_seg -> attn out
  bf16* h1b = (bf16*)alloc((size_t)CR * Md * sizeof(bf16));
  bf16* h2b = (bf16*)alloc((size_t)CR * Md * sizeof(bf16));
  bf16* Bb  = (bf16*)alloc(RB);          // retrieved -> ao
  bf16* KVx = (bf16*)alloc(2 * RB);      // [k_x|v_x] -> gate
  bf16* KVr = (bf16*)alloc(2 * RB);      // [k_r|v_r]
  bf16* Cc  = (bf16*)alloc(RB);          // gin -> t

  dim3 blk(256);
  auto g128 = [](int M_, int N_) { return dim3((unsigned)(N_ / 128), (unsigned)(M_ / 128)); };
  auto g64  = [](int M_, int N_) { return dim3((unsigned)((N_ + 63) / 64), (unsigned)((M_ + 63) / 64)); };

  detect_kernel<<<1, 64, 0, stream>>>((const unsigned short*)d_in[24], flag);
  for (int i = 1; i < 30; ++i) {
    int n = in_sizes[i];
    conv_kernel<<<dim3((n + 255) / 256), blk, 0, stream>>>(d_in[i], nb[i], n, 0, flag);
  }

  const bf16 *pm = nb[1], *Wq = nb[2], *Wk = nb[3], *Wv = nb[4];
  const bf16 *mem_W1 = nb[5], *mem_b1 = nb[6], *ln1g = nb[7], *ln1b = nb[8];
  const bf16 *mem_W2 = nb[9], *mem_b2 = nb[10], *ln2g = nb[11], *ln2b = nb[12];
  const bf16 *mem_oW = nb[13], *mem_ob = nb[14], *mstate = nb[15];
  const bf16 *mhaWq = nb[16], *mhabq = nb[17], *mhaWk = nb[18], *mhabk = nb[19];
  const bf16 *mhaWv = nb[20], *mhabv = nb[21], *mhaWo = nb[22], *mhabo = nb[23];
  const bf16 *gn_g = nb[24], *gn_b = nb[25], *gateW = nb[26], *gateb = nb[27];
  const bf16 *outW = nb[28], *outb = nb[29];

  // combined K/V weights into packed [2048][1024], shared bias vector, persistent rows
  gemm_kernel<bf16, bf16, ACT_NONE, false><<<g64(Cd, Cd), blk, 0, stream>>>(mhaWk, Wk, nullptr, Wkv, Cd, Cd, Cd);
  gemm_kernel<bf16, bf16, ACT_NONE, false><<<g64(Cd, Cd), blk, 0, stream>>>(mhaWv, Wv, nullptr, Wkv + (size_t)Cd * Cd, Cd, Cd, Cd);
  pack_bias2<<<8, blk, 0, stream>>>(mhabk, mhabv, bias2);
  gemm_kernel<bf16, bf16, ACT_NONE, true><<<g64(4, Cd), blk, 0, stream>>>(pm, Wkv, mhabk, kp, 4, Cd, Cd);
  gemm_kernel<bf16, bf16, ACT_NONE, true><<<g64(4, Cd), blk, 0, stream>>>(pm, Wkv + (size_t)Cd * Cd, mhabv, vp, 4, Cd, Cd);

  for (int r0 = 0; r0 < R; r0 += CR) {
    const int cr = (R - r0 < CR) ? (R - r0) : CR;
    const int n = cr * Cd;
    conv_kernel<<<dim3((n + 255) / 256), blk, 0, stream>>>(d_in[0], Xc, n, (size_t)r0 * Cd, flag);

    // q_seg -> memory net -> retrieved (Bb)
    mgemm<bf16, ACT_NONE, false><<<g128(cr, Cd), blk, 0, stream>>>(Xc, Wq, nullptr, QS, cr, Cd, Cd, Cd, Cd);
    mgemm<bf16, ACT_SILU, true><<<g128(cr, Md), blk, 0, stream>>>(QS, mem_W1, mem_b1, h1b, cr, Md, Cd, Cd, Md);
    ln_kernel<bf16, bf16, false, 128, 128><<<cr, 128, 0, stream>>>(h1b, ln1g, ln1b, nullptr, h2b);
    mgemm<bf16, ACT_NONE, true><<<g128(cr, Md), blk, 0, stream>>>(h2b, mem_W2, mem_b2, h1b, cr, Md, Md, Md, Md);
    ln_kernel<bf16, bf16, true, 128, 128><<<cr, 128, 0, stream>>>(h1b, ln2g, ln2b, mstate, h2b);
    mgemm<bf16, ACT_NONE, true><<<g128(cr, Cd), blk, 0, stream>>>(h2b, mem_oW, mem_ob, Bb, cr, Cd, Md, Md, Cd);

    // projections: KVx (from Xc), q (into Xc, AFTER KVx), KVr (from retrieved)
    mgemm<bf16, ACT_NONE, true><<<g128(cr, 2048), blk, 0, stream>>>(Xc, Wkv, bias2, KVx, cr, 2048, Cd, Cd, 2048);
    mgemm<bf16, ACT_NONE, true><<<g128(cr, Cd), blk, 0, stream>>>(QS, mhaWq, mhabq, Xc, cr, Cd, Cd, Cd, Cd);
    mgemm<bf16, ACT_NONE, true><<<g128(cr, 2048), blk, 0, stream>>>(Bb, Wkv, bias2, KVr, cr, 2048, Cd, Cd, 2048);

    attn_kernel<<<dim3((cr / 64) * 8), dim3(512), 0, stream>>>(Xc, KVr, KVx, kp, vp, QS);

    // output projection, gate, combine, final
    mgemm<bf16, ACT_NONE, true><<<g128(cr, Cd), blk, 0, stream>>>(QS, mhaWo, mhabo, Bb, cr, Cd, Cd, Cd, Cd);
    ln_kernel<bf16, bf16, false, 1024, 256><<<cr, 256, 0, stream>>>(Bb, gn_g, gn_b, nullptr, Cc);
    mgemm<bf16, ACT_SIGMOID, true><<<g128(cr, Cd), blk, 0, stream>>>(Cc, gateW, gateb, KVx, cr, Cd, Cd, Cd, Cd);
    combine_kernel<<<dim3(n / 256), blk, 0, stream>>>(KVx, Bb, d_in[0], (size_t)r0 * Cd, flag, Cc, n);
    mgemm<float, ACT_NONE, true><<<g128(cr, Cd), blk, 0, stream>>>(Cc, outW, outb, (float*)d_out + (size_t)r0 * Cd, cr, Cd, Cd, Cd, Cd);
  }
}

// Round 8
// 1213.712 us; speedup vs baseline: 1.3064x; 1.3064x over previous
//
#include <hip/hip_runtime.h>
#include <hip/hip_bf16.h>
#include <math.h>

// TitanLongTermMemory — round 8: overhead surgery.
// r7: preamble VALU weight-combines = 218us/launch (top-5!), ~30 conv micro-
// launches, unbalanced 14336+2048 chunks. This round: combines via transpose+
// MFMA, one fused conv kernel, balanced chunks, N=3072 packed x-projection
// ([q_seg|k_x|v_x] in one GEMM), gate*ao+x fused into gate-GEMM epilogue.

using bf16 = __hip_bfloat16;

typedef __attribute__((ext_vector_type(8))) short bf16x8;
typedef __attribute__((ext_vector_type(4))) float f32x4;

__device__ __forceinline__ float ldf(const bf16* p) { return __bfloat162float(*p); }
__device__ __forceinline__ float ldf(const float* p) { return *p; }
__device__ __forceinline__ void stf(bf16* p, float v) { *p = __float2bfloat16(v); }
__device__ __forceinline__ void stf(float* p, float v) { *p = v; }
__device__ __forceinline__ float b2f(const bf16& b) { return __bfloat162float(b); }

enum { ACT_NONE = 0, ACT_SILU = 1, ACT_SIGMOID = 2, ACT_GATE = 3 };

__global__ void detect_kernel(const unsigned short* g, int* flag) {
  if (threadIdx.x == 0) *flag = (g[0] != 0) ? 1 : 0;
}

// ---- single fused dtype-normalize for all non-x inputs ----------------------
struct ConvArgs {
  const void* src[29];
  bf16* dst[29];
  int n[29];
  int bstart[30];
};

__global__ __launch_bounds__(256) void convall_kernel(ConvArgs a, const int* __restrict__ flag) {
  int b = blockIdx.x;
  int ti = 0;
  while (ti < 28 && b >= a.bstart[ti + 1]) ++ti;
  int i = (b - a.bstart[ti]) * 256 + threadIdx.x;
  if (i >= a.n[ti]) return;
  if (*flag) a.dst[ti][i] = ((const bf16*)a.src[ti])[i];
  else a.dst[ti][i] = __float2bfloat16(((const float*)a.src[ti])[i]);
}

__global__ __launch_bounds__(256) void conv_kernel(
    const void* __restrict__ src, bf16* __restrict__ dst, int n, size_t src_off,
    const int* __restrict__ flag) {
  int i = blockIdx.x * 256 + threadIdx.x;
  if (i >= n) return;
  if (*flag) dst[i] = ((const bf16*)src)[src_off + i];
  else dst[i] = __float2bfloat16(((const float*)src)[src_off + i]);
}

// bias3 = [0(1024) | bk(1024) | bv(1024)]
__global__ __launch_bounds__(256) void pack_bias3(
    const bf16* __restrict__ bk, const bf16* __restrict__ bv, bf16* __restrict__ o) {
  int j = blockIdx.x * 256 + threadIdx.x;
  if (j >= 3072) return;
  float v = 0.f;
  if (j >= 2048) v = b2f(bv[j - 2048]);
  else if (j >= 1024) v = b2f(bk[j - 1024]);
  o[j] = __float2bfloat16(v);
}

// 64x64-tile transpose: dst[n][k] = src[k][n], 1024x1024
__global__ __launch_bounds__(256) void transpose_kernel(
    const bf16* __restrict__ srcb, bf16* __restrict__ dstb) {
  __shared__ unsigned short t[64][72];  // 144B row stride (16B-aligned)
  const unsigned short* src = (const unsigned short*)srcb;
  unsigned short* dst = (unsigned short*)dstb;
  const int r0 = blockIdx.y * 64, c0 = blockIdx.x * 64;
  for (int e = threadIdx.x; e < 64 * 8; e += 256) {
    int r = e >> 3, c8 = e & 7;
    uint4 v = *(const uint4*)(src + (size_t)(r0 + r) * 1024 + c0 + c8 * 8);
    *(uint4*)&t[r][c8 * 8] = v;
  }
  __syncthreads();
  for (int e = threadIdx.x; e < 64 * 8; e += 256) {
    int c = e >> 3, r8 = (e & 7) * 8;
    unsigned short v[8];
#pragma unroll
    for (int j = 0; j < 8; ++j) v[j] = t[r8 + j][c];
    *(uint4*)(dst + (size_t)(c0 + c) * 1024 + r0 + r8) = *(uint4*)v;
  }
}

// ---------------- MFMA GEMM: C[M,N] = act(A[M,K] @ B[N,K]^T + bias) ----------
__device__ __forceinline__ void gl_lds16(const short* g, short* l) {
  __builtin_amdgcn_global_load_lds(
      (const __attribute__((address_space(1))) void*)g,
      (__attribute__((address_space(3))) void*)l, 16, 0, 0);
}

// ACT_GATE epilogue: t = sigmoid(acc+bias) * ao[m,n] + x[m,n]; C bf16.
template <typename TC, int ACT, bool HAS_BIAS>
__global__ __launch_bounds__(256) void mgemm(
    const bf16* __restrict__ Ab, const bf16* __restrict__ Bw,
    const bf16* __restrict__ bias, TC* __restrict__ C,
    int M, int N, int K, int lda, int ldc,
    const bf16* __restrict__ ao, const void* __restrict__ xsrc, size_t xoff,
    const int* __restrict__ flag)
{
  __shared__ short As[128 * 32];
  __shared__ short Bs[128 * 32];
  const short* A = (const short*)Ab;
  const short* B = (const short*)Bw;
  const int tid = threadIdx.x;
  const int m0 = blockIdx.y * 128, n0 = blockIdx.x * 128;
  const int wave = tid >> 6, lane = tid & 63;
  const int wm = (wave & 1) * 64, wn = (wave >> 1) * 64;
  const int fm = lane & 15;
  const int fk = (lane >> 4) * 8;

  const int srow = tid >> 2, scol = (tid & 3) * 8;
  const short* gA0 = A + (size_t)(m0 + srow) * lda + scol;
  const short* gA1 = A + (size_t)(m0 + 64 + srow) * lda + scol;
  const short* gB0 = B + (size_t)(n0 + srow) * K + scol;
  const short* gB1 = B + (size_t)(n0 + 64 + srow) * K + scol;
  short* lA0 = As + tid * 8;
  short* lA1 = As + (256 + tid) * 8;
  short* lB0 = Bs + tid * 8;
  short* lB1 = Bs + (256 + tid) * 8;

  f32x4 acc[4][4] = {};

  for (int k0 = 0; k0 < K; k0 += 32) {
    gl_lds16(gA0 + k0, lA0);
    gl_lds16(gA1 + k0, lA1);
    gl_lds16(gB0 + k0, lB0);
    gl_lds16(gB1 + k0, lB1);
    __syncthreads();
    bf16x8 af[4], bfr[4];
#pragma unroll
    for (int i = 0; i < 4; ++i)
      af[i] = *(const bf16x8*)&As[(wm + i * 16 + fm) * 32 + fk];
#pragma unroll
    for (int j = 0; j < 4; ++j)
      bfr[j] = *(const bf16x8*)&Bs[(wn + j * 16 + fm) * 32 + fk];
#pragma unroll
    for (int i = 0; i < 4; ++i)
#pragma unroll
      for (int j = 0; j < 4; ++j)
        acc[i][j] = __builtin_amdgcn_mfma_f32_16x16x32_bf16(af[i], bfr[j], acc[i][j], 0, 0, 0);
    __syncthreads();
  }

  const int rg = (lane >> 4) * 4;
#pragma unroll
  for (int i = 0; i < 4; ++i) {
#pragma unroll
    for (int j = 0; j < 4; ++j) {
      const int n = n0 + wn + j * 16 + fm;
      float bv = 0.f;
      if (HAS_BIAS) bv = b2f(bias[n]);
#pragma unroll
      for (int r = 0; r < 4; ++r) {
        const int m = m0 + wm + i * 16 + rg + r;
        float v = acc[i][j][r] + bv;
        if (ACT == ACT_SILU) v = v / (1.f + __expf(-v));
        if (ACT == ACT_SIGMOID) v = 1.f / (1.f + __expf(-v));
        if (ACT == ACT_GATE) {
          v = 1.f / (1.f + __expf(-v));
          const size_t e = (size_t)m * 1024 + n;
          const float xv = *flag ? b2f(((const bf16*)xsrc)[xoff + e])
                                 : ((const float*)xsrc)[xoff + e];
          v = v * b2f(ao[e]) + xv;
        }
        stf(&C[(size_t)m * ldc + n], v);
      }
    }
  }
}

// ---------------- VALU GEMM (kp/vp, M=4) -------------------------------------
template <typename TA, typename TC, int ACT, bool TRANS_B>
__global__ __launch_bounds__(256) void gemm_kernel(
    const TA* __restrict__ A, const bf16* __restrict__ B,
    const bf16* __restrict__ bias, TC* __restrict__ C,
    int M, int N, int K)
{
  __shared__ float As[16][68];
  __shared__ float Bs[16][68];
  const int tid = threadIdx.x;
  const int tx = tid & 15;
  const int ty = tid >> 4;
  const int m0 = blockIdx.y * 64;
  const int n0 = blockIdx.x * 64;

  float acc[4][4] = {};

  for (int k0 = 0; k0 < K; k0 += 16) {
#pragma unroll
    for (int i = 0; i < 4; ++i) {
      int e = tid + 256 * i;
      int m = e >> 4, kk = e & 15;
      float v = 0.f;
      if (m0 + m < M) v = ldf(&A[(size_t)(m0 + m) * K + k0 + kk]);
      As[kk][m] = v;
    }
#pragma unroll
    for (int i = 0; i < 4; ++i) {
      int e = tid + 256 * i;
      if (TRANS_B) {
        int n = e >> 4, kk = e & 15;
        float v = 0.f;
        if (n0 + n < N) v = ldf(&B[(size_t)(n0 + n) * K + k0 + kk]);
        Bs[kk][n] = v;
      } else {
        int kk = e >> 6, n = e & 63;
        float v = 0.f;
        if (n0 + n < N) v = ldf(&B[(size_t)(k0 + kk) * N + n0 + n]);
        Bs[kk][n] = v;
      }
    }
    __syncthreads();
#pragma unroll
    for (int kk = 0; kk < 16; ++kk) {
      const float4 av = *reinterpret_cast<const float4*>(&As[kk][ty * 4]);
      const float4 bv = *reinterpret_cast<const float4*>(&Bs[kk][tx * 4]);
      const float a[4] = {av.x, av.y, av.z, av.w};
      const float b[4] = {bv.x, bv.y, bv.z, bv.w};
#pragma unroll
      for (int i = 0; i < 4; ++i)
#pragma unroll
        for (int j = 0; j < 4; ++j) acc[i][j] += a[i] * b[j];
    }
    __syncthreads();
  }

#pragma unroll
  for (int i = 0; i < 4; ++i) {
    int m = m0 + ty * 4 + i;
    if (m >= M) continue;
#pragma unroll
    for (int j = 0; j < 4; ++j) {
      int n = n0 + tx * 4 + j;
      if (n >= N) continue;
      float v = acc[i][j];
      if (bias) v += b2f(bias[n]);
      stf(&C[(size_t)m * N + n], v);
    }
  }
}

// Row LayerNorm over width W; optional post-LN add of a bf16 vector.
template <typename TI, typename TO, bool ADD, int W, int BS>
__global__ __launch_bounds__(BS) void ln_kernel(
    const TI* __restrict__ in, const bf16* __restrict__ g, const bf16* __restrict__ b,
    const bf16* __restrict__ addv, TO* __restrict__ out, int ldin)
{
  __shared__ float red[BS];
  const int row = blockIdx.x;
  const TI* rin = in + (size_t)row * ldin;
  TO* rout = out + (size_t)row * W;
  const int NP = W / BS;
  float v[NP];
  float s = 0.f;
#pragma unroll
  for (int i = 0; i < NP; ++i) { v[i] = ldf(&rin[threadIdx.x + i * BS]); s += v[i]; }
  red[threadIdx.x] = s; __syncthreads();
  for (int o = BS / 2; o > 0; o >>= 1) {
    if (threadIdx.x < o) red[threadIdx.x] += red[threadIdx.x + o];
    __syncthreads();
  }
  const float mean = red[0] / W;
  __syncthreads();
  float sq = 0.f;
#pragma unroll
  for (int i = 0; i < NP; ++i) { float d = v[i] - mean; sq += d * d; }
  red[threadIdx.x] = sq; __syncthreads();
  for (int o = BS / 2; o > 0; o >>= 1) {
    if (threadIdx.x < o) red[threadIdx.x] += red[threadIdx.x + o];
    __syncthreads();
  }
  const float rstd = rsqrtf(red[0] / W + 1e-5f);
#pragma unroll
  for (int i = 0; i < NP; ++i) {
    int c = threadIdx.x + i * BS;
    float o_ = (v[i] - mean) * rstd * b2f(g[c]) + b2f(b[c]);
    if (ADD) o_ += b2f(addv[c]);
    stf(&rout[c], o_);
  }
}

// ---------------- MFMA attention (r7 structure + source strides) ------------
__global__ __launch_bounds__(512) void attn_kernel(
    const bf16* __restrict__ qg, const bf16* __restrict__ krv, int str_r,
    const bf16* __restrict__ kxv, int str_x, const bf16* __restrict__ kpg,
    const bf16* __restrict__ vpg, bf16* __restrict__ outg)
{
  __shared__ short qs[4 * 64 * 32];
  __shared__ short ksl[4 * 144 * 32];
  __shared__ short vt[128 * 168];
  __shared__ short pl[64 * 168];

  const int tid = threadIdx.x;
  const int seg = blockIdx.x >> 3, h = blockIdx.x & 7;
  const unsigned short* q = (const unsigned short*)qg;
  const unsigned short* kv_r = (const unsigned short*)krv + (size_t)seg * 64 * str_r + h * 128;
  const unsigned short* kv_x = (const unsigned short*)kxv + (size_t)seg * 64 * str_x + h * 128;
  const unsigned short* kp = (const unsigned short*)kpg;
  const unsigned short* vp = (const unsigned short*)vpg;
  const size_t qbase = (size_t)seg * 64 * 1024 + h * 128;

  for (int ch = tid; ch < 64 * 16; ch += 512) {
    int row = ch >> 4, k8 = ch & 15;
    uint4 v = *(const uint4*)(q + qbase + (size_t)row * 1024 + k8 * 8);
    *(uint4*)&qs[((k8 >> 2) * 64 + row) * 32 + (k8 & 3) * 8] = v;
  }
  for (int ch = tid; ch < 132 * 16; ch += 512) {
    int t = ch >> 4, k8 = ch & 15;
    const unsigned short* src;
    if (t < 64) src = kv_r + (size_t)t * str_r;
    else if (t < 68) src = kp + (size_t)(t - 64) * 1024 + h * 128;
    else src = kv_x + (size_t)(t - 68) * str_x;
    uint4 v = *(const uint4*)(src + k8 * 8);
    *(uint4*)&ksl[((k8 >> 2) * 144 + t) * 32 + (k8 & 3) * 8] = v;
  }
  __syncthreads();

  const int wave = tid >> 6, lane = tid & 63;
  const int fm = lane & 15, fq = lane >> 4;

  if (wave < 4) {
    const int s0 = wave * 16;
    f32x4 acc[10];
#pragma unroll
    for (int tt = 0; tt < 10; ++tt) acc[tt] = (f32x4){0.f, 0.f, 0.f, 0.f};
#pragma unroll
    for (int kb = 0; kb < 4; ++kb) {
      const bf16x8 a = *(const bf16x8*)&qs[(kb * 64 + s0 + fm) * 32 + fq * 8];
#pragma unroll
      for (int tt = 0; tt < 9; ++tt) {
        const bf16x8 b = *(const bf16x8*)&ksl[(kb * 144 + tt * 16 + fm) * 32 + fq * 8];
        acc[tt] = __builtin_amdgcn_mfma_f32_16x16x32_bf16(a, b, acc[tt], 0, 0, 0);
      }
    }
    const float scale = 0.08838834764831845f;
#pragma unroll
    for (int r = 0; r < 4; ++r) {
      float m = -3.0e38f;
#pragma unroll
      for (int tt = 0; tt < 9; ++tt) {
        int t = tt * 16 + fm;
        if (t < 132) m = fmaxf(m, acc[tt][r] * scale);
      }
      for (int d = 1; d < 16; d <<= 1) m = fmaxf(m, __shfl_xor(m, d));
      float e[10];
      float sum = 0.f;
#pragma unroll
      for (int tt = 0; tt < 10; ++tt) {
        int t = tt * 16 + fm;
        float ev = 0.f;
        if (t < 132) ev = __expf(acc[tt][r] * scale - m);
        e[tt] = ev; sum += ev;
      }
      for (int d = 1; d < 16; d <<= 1) sum += __shfl_xor(sum, d);
      const float inv = 1.f / sum;
      const int s = s0 + fq * 4 + r;
#pragma unroll
      for (int tt = 0; tt < 10; ++tt) {
        bf16 pv = __float2bfloat16(e[tt] * inv);
        pl[s * 168 + tt * 16 + fm] = *(const short*)&pv;
      }
    }
  } else {
    for (int ch = tid - 256; ch < 132 * 32; ch += 256) {
      int t = ch >> 5, d4 = (ch & 31) * 4;
      const unsigned short* src;
      if (t < 64) src = kv_r + 1024 + (size_t)t * str_r;
      else if (t < 68) src = vp + (size_t)(t - 64) * 1024 + h * 128;
      else src = kv_x + 1024 + (size_t)(t - 68) * str_x;
      uint2 w = *(const uint2*)(src + d4);
      vt[(d4 + 0) * 168 + t] = (short)(w.x & 0xffffu);
      vt[(d4 + 1) * 168 + t] = (short)(w.x >> 16);
      vt[(d4 + 2) * 168 + t] = (short)(w.y & 0xffffu);
      vt[(d4 + 3) * 168 + t] = (short)(w.y >> 16);
    }
    for (int ch = tid - 256; ch < 128 * 32; ch += 256) {
      int d = ch >> 5, tp = 132 + (ch & 31);
      vt[d * 168 + tp] = 0;
    }
  }
  __syncthreads();

  const int dt = wave;
  bf16x8 af[5];
#pragma unroll
  for (int kb = 0; kb < 5; ++kb)
    af[kb] = *(const bf16x8*)&vt[(dt * 16 + fm) * 168 + kb * 32 + fq * 8];
#pragma unroll
  for (int st = 0; st < 4; ++st) {
    f32x4 o = (f32x4){0.f, 0.f, 0.f, 0.f};
#pragma unroll
    for (int kb = 0; kb < 5; ++kb) {
      const bf16x8 bp = *(const bf16x8*)&pl[(st * 16 + fm) * 168 + kb * 32 + fq * 8];
      o = __builtin_amdgcn_mfma_f32_16x16x32_bf16(af[kb], bp, o, 0, 0, 0);
    }
    const int s = st * 16 + fm;
    bf16 b0 = __float2bfloat16(o[0]), b1 = __float2bfloat16(o[1]);
    bf16 b2 = __float2bfloat16(o[2]), b3 = __float2bfloat16(o[3]);
    uint2 w;
    w.x = ((unsigned)(*(unsigned short*)&b1) << 16) | (*(unsigned short*)&b0);
    w.y = ((unsigned)(*(unsigned short*)&b3) << 16) | (*(unsigned short*)&b2);
    *(uint2*)((unsigned short*)outg + qbase + (size_t)s * 1024 + dt * 16 + fq * 4) = w;
  }
}

extern "C" void kernel_launch(void* const* d_in, const int* in_sizes, int n_in,
                              void* d_out, int out_size, void* d_ws, size_t ws_size,
                              hipStream_t stream)
{
  (void)n_in; (void)out_size;
  const int R = 16384, Cd = 1024, Md = 128;

  char* ws = (char*)d_ws;
  size_t off = 0;
  auto alloc = [&](size_t bytes) -> void* {
    void* p = ws + off;
    off += (bytes + 255) & ~(size_t)255;
    return p;
  };

  int* flag = (int*)alloc(256);
  // packed projection weights [Wq | Wkk | Wvv] rows (3072 x 1024)
  bf16* Wq3   = (bf16*)alloc((size_t)3072 * Cd * sizeof(bf16));
  bf16* bias3 = (bf16*)alloc(3072 * sizeof(bf16));
  bf16* WkT   = (bf16*)alloc((size_t)Cd * Cd * sizeof(bf16));
  bf16* WvT   = (bf16*)alloc((size_t)Cd * Cd * sizeof(bf16));
  bf16* kp    = (bf16*)alloc((size_t)4 * Cd * sizeof(bf16));
  bf16* vp    = (bf16*)alloc((size_t)4 * Cd * sizeof(bf16));
  bf16* nb[30];
  nb[0] = nullptr;
  for (int i = 1; i < 30; ++i) nb[i] = (bf16*)alloc((size_t)in_sizes[i] * sizeof(bf16));
  nb[2] = Wq3;  // Wq converts straight into the packed block (rows 0..1023)
  const size_t fixed_end = off;

  // balanced chunk sizing; per-row scratch = 16896 B
  size_t avail = (ws_size > fixed_end + (1u << 20)) ? (ws_size - fixed_end - (1u << 20)) : 0;
  int crmax = (int)(avail / 16896);
  if (crmax > R) crmax = R;
  if (crmax < 128) crmax = 128;
  int nch = (R + crmax - 1) / crmax;
  int CR = ((R / nch + 127) / 128) * 128;
  while (CR * nch < R) CR += 128;

  const size_t RB = (size_t)CR * Cd * sizeof(bf16);
  bf16* Xc  = (bf16*)alloc(RB);              // x(bf16) -> attn out -> t
  bf16* QS3 = (bf16*)alloc(3 * RB);          // [q_seg | k_x | v_x]
  bf16* h1b = (bf16*)alloc((size_t)CR * Md * sizeof(bf16));
  bf16* h2b = (bf16*)alloc((size_t)CR * Md * sizeof(bf16));
  bf16* Bb  = (bf16*)alloc(RB);              // retrieved -> ao
  bf16* KVr = (bf16*)alloc(2 * RB);          // [k_r | v_r]
  bf16* Cc  = (bf16*)alloc(RB);              // q -> gin

  dim3 blk(256);
  auto g128 = [](int M_, int N_) { return dim3((unsigned)(N_ / 128), (unsigned)(M_ / 128)); };

  // ---- preamble ----
  detect_kernel<<<1, 64, 0, stream>>>((const unsigned short*)d_in[24], flag);
  {
    ConvArgs a;
    int bs = 0;
    for (int i = 1; i < 30; ++i) {
      a.src[i - 1] = d_in[i];
      a.dst[i - 1] = nb[i];
      a.n[i - 1] = in_sizes[i];
      a.bstart[i - 1] = bs;
      bs += (in_sizes[i] + 255) / 256;
    }
    a.bstart[29] = bs;
    convall_kernel<<<dim3((unsigned)bs), blk, 0, stream>>>(a, flag);
  }
  const bf16 *pm = nb[1], *Wk = nb[3], *Wv = nb[4];
  const bf16 *mem_W1 = nb[5], *mem_b1 = nb[6], *ln1g = nb[7], *ln1b = nb[8];
  const bf16 *mem_W2 = nb[9], *mem_b2 = nb[10], *ln2g = nb[11], *ln2b = nb[12];
  const bf16 *mem_oW = nb[13], *mem_ob = nb[14], *mstate = nb[15];
  const bf16 *mhaWq = nb[16], *mhabq = nb[17], *mhaWk = nb[18], *mhabk = nb[19];
  const bf16 *mhaWv = nb[20], *mhabv = nb[21], *mhaWo = nb[22], *mhabo = nb[23];
  const bf16 *gn_g = nb[24], *gn_b = nb[25], *gateW = nb[26], *gateb = nb[27];
  const bf16 *outW = nb[28], *outb = nb[29];
  bf16* Wkk = Wq3 + (size_t)1024 * Cd;
  bf16* Wvv = Wq3 + (size_t)2048 * Cd;

  transpose_kernel<<<dim3(16, 16), blk, 0, stream>>>(Wk, WkT);
  transpose_kernel<<<dim3(16, 16), blk, 0, stream>>>(Wv, WvT);
  mgemm<bf16, ACT_NONE, false><<<g128(Cd, Cd), blk, 0, stream>>>(
      mhaWk, WkT, nullptr, Wkk, Cd, Cd, Cd, Cd, Cd, nullptr, nullptr, 0, nullptr);
  mgemm<bf16, ACT_NONE, false><<<g128(Cd, Cd), blk, 0, stream>>>(
      mhaWv, WvT, nullptr, Wvv, Cd, Cd, Cd, Cd, Cd, nullptr, nullptr, 0, nullptr);
  pack_bias3<<<12, blk, 0, stream>>>(mhabk, mhabv, bias3);
  gemm_kernel<bf16, bf16, ACT_NONE, true><<<dim3(16, 1), blk, 0, stream>>>(pm, Wkk, mhabk, kp, 4, Cd, Cd);
  gemm_kernel<bf16, bf16, ACT_NONE, true><<<dim3(16, 1), blk, 0, stream>>>(pm, Wvv, mhabv, vp, 4, Cd, Cd);

  for (int r0 = 0; r0 < R; r0 += CR) {
    const int cr = (R - r0 < CR) ? (R - r0) : CR;
    const int n = cr * Cd;
    conv_kernel<<<dim3((n + 255) / 256), blk, 0, stream>>>(d_in[0], Xc, n, (size_t)r0 * Cd, flag);

    // packed x-projection: [q_seg | k_x | v_x]
    mgemm<bf16, ACT_NONE, true><<<g128(cr, 3072), blk, 0, stream>>>(
        Xc, Wq3, bias3, QS3, cr, 3072, Cd, Cd, 3072, nullptr, nullptr, 0, nullptr);

    // memory net on q_seg (lda = 3072) -> retrieved (Bb)
    mgemm<bf16, ACT_SILU, true><<<g128(cr, Md), blk, 0, stream>>>(
        QS3, mem_W1, mem_b1, h1b, cr, Md, Cd, 3072, Md, nullptr, nullptr, 0, nullptr);
    ln_kernel<bf16, bf16, false, 128, 128><<<cr, 128, 0, stream>>>(h1b, ln1g, ln1b, nullptr, h2b, Md);
    mgemm<bf16, ACT_NONE, true><<<g128(cr, Md), blk, 0, stream>>>(
        h2b, mem_W2, mem_b2, h1b, cr, Md, Md, Md, Md, nullptr, nullptr, 0, nullptr);
    ln_kernel<bf16, bf16, true, 128, 128><<<cr, 128, 0, stream>>>(h1b, ln2g, ln2b, mstate, h2b, Md);
    mgemm<bf16, ACT_NONE, true><<<g128(cr, Cd), blk, 0, stream>>>(
        h2b, mem_oW, mem_ob, Bb, cr, Cd, Md, Md, Cd, nullptr, nullptr, 0, nullptr);

    // q (from q_seg) and KVr (from retrieved)
    mgemm<bf16, ACT_NONE, true><<<g128(cr, Cd), blk, 0, stream>>>(
        QS3, mhaWq, mhabq, Cc, cr, Cd, Cd, 3072, Cd, nullptr, nullptr, 0, nullptr);
    mgemm<bf16, ACT_NONE, true><<<g128(cr, 2048), blk, 0, stream>>>(
        Bb, Wkk, bias3 + 1024, KVr, cr, 2048, Cd, Cd, 2048, nullptr, nullptr, 0, nullptr);

    attn_kernel<<<dim3((cr / 64) * 8), dim3(512), 0, stream>>>(
        Cc, KVr, 2048, QS3 + 1024, 3072, kp, vp, Xc);

    // ao, gate-norm, fused gate*ao+x, final projection
    mgemm<bf16, ACT_NONE, true><<<g128(cr, Cd), blk, 0, stream>>>(
        Xc, mhaWo, mhabo, Bb, cr, Cd, Cd, Cd, Cd, nullptr, nullptr, 0, nullptr);
    ln_kernel<bf16, bf16, false, 1024, 256><<<cr, 256, 0, stream>>>(Bb, gn_g, gn_b, nullptr, Cc, Cd);
    mgemm<bf16, ACT_GATE, true><<<g128(cr, Cd), blk, 0, stream>>>(
        Cc, gateW, gateb, Xc, cr, Cd, Cd, Cd, Cd, Bb, d_in[0], (size_t)r0 * Cd, flag);
    mgemm<float, ACT_NONE, true><<<g128(cr, Cd), blk, 0, stream>>>(
        Xc, outW, outb, (float*)d_out + (size_t)r0 * Cd, cr, Cd, Cd, Cd, Cd,
        nullptr, nullptr, 0, nullptr);
  }
}